// Round 8
// baseline (365.738 us; speedup 1.0000x reference)
//
#include <hip/hip_runtime.h>
#include <hip/hip_bf16.h>

#define BB 32
#define LL 1024
#define DD 768

typedef short bf16x8 __attribute__((ext_vector_type(8)));
typedef float f32x4 __attribute__((ext_vector_type(4)));

// RNE f32 -> bf16 as raw ushort (bit-twiddle; same rounding as the verified
// R0-R2 kernels' f2bf — inputs are finite normals, no NaN handling needed).
// NOTE: __builtin_bit_cast(unsigned, __hip_bfloat162) does NOT compile on
// this ROCm (type not trivially copyable) — hence the integer path.
__device__ __forceinline__ unsigned f2bf_u(float f) {
    unsigned u = __builtin_bit_cast(unsigned, f);
    u += 0x7fffu + ((u >> 16) & 1u);
    return u >> 16;
}
__device__ __forceinline__ unsigned pack_bf16(float lo, float hi) {
    return f2bf_u(lo) | (f2bf_u(hi) << 16);
}

// ---------------------------------------------------------------------------
// FUSED kernel: fp32 Q,K + w1,w2,w3  ->  out[b,q,k] = ql[q] + kl[k] + dot
//
// The separate convert kernel (95 us at 33% of copy BW) existed only to
// produce bf16 operands the GEMM re-read. Fused: each block reg-stages its
// fp32 tiles (global->VGPR), converts in-register (K scaled by w3), ds_writes
// into the SAME verified XOR-swizzled LDS layout (involution p = l^((r>>1)&3)
// works identically from the write side), and accumulates the w1/w2 logit
// dots on the data while it's in registers. No bf16 intermediate, no qlog/
// klog arrays, no second kernel. HBM: ~330 MB total vs ~540 MB before.
// (R3/R5/R6/R7 = acquisition timeouts; R4 = bit_cast compile error, fixed.
// This is the unchanged resubmit of the fused structure.)
//
// Reg-staging advantage (T14): VGPR-landing loads cross barriers freely (no
// vmcnt discipline needed at all) -> 2-slot LDS ring (64 KB), one barrier +
// one lgkmcnt(0) per tile. Per tile: frags -> lgkm -> 32 MFMA (covers tile
// t+1's loads in flight) -> cvt+ds_write t+1 -> issue loads t+2 -> barrier.
//
// Geometry unchanged from the verified R2 kernel: 256x256 tile, 8 waves
// (2Mx4N, 128x64/wave), BK=32, acc[8][4], batch->XCD affinity swizzle,
// fragment-read formulas byte-identical (SQ_LDS_BANK_CONFLICT = 0 verified).
//
// Staging map: thread t <-> (row sr = t&255, half hh = t>>8). Thread loads
// fp32 cols [k0+hh*16, +16) of its row each tile -> its logit partial covers
// a fixed 384-col half; 2-way LDS reduce at the end completes the dot.
// hh is wave-uniform (readfirstlane -> SGPR) so w1/w2/w3 reads are uniform
// scalar loads on the constant-cache path, not per-lane vmem.
// ---------------------------------------------------------------------------
__global__ __launch_bounds__(512, 2) void trilinear_fused(
    const float* __restrict__ Q, const float* __restrict__ K,
    const float* __restrict__ w1, const float* __restrict__ w2,
    const float* __restrict__ w3,
    float* __restrict__ out)
{
    __shared__ __align__(16) unsigned short As[2][256 * 32];   // 2 x 16 KB
    __shared__ __align__(16) unsigned short Bs[2][256 * 32];   // 2 x 16 KB
    __shared__ float redq[512], redk[512];                     // 4 KB
    __shared__ float qls[256], kls[256];                       // 2 KB

    const int tid  = threadIdx.x;
    const int w    = tid >> 6, lane = tid & 63;
    const int wq   = w >> 2, wk = w & 3;          // 2 (M) x 4 (N) waves

    // 512 blocks: id = g + 8*(t0 + 16*(b>>3)), g = b&7, t0 = qt*4+kt
    const int id = blockIdx.x;
    const int g  = id & 7;
    const int j  = id >> 3;            // 0..63
    const int b  = g + ((j >> 4) << 3);
    const int t0 = j & 15;
    const int qt = t0 >> 2, kt = t0 & 3;

    const float* Qg = Q + ((size_t)b * LL + qt * 256) * DD;
    const float* Kg = K + ((size_t)b * LL + kt * 256) * DD;

    // staging identity
    const int sr = tid & 255;                                  // tile row
    const int hh = __builtin_amdgcn_readfirstlane(tid >> 8);   // 16-col half (SGPR)
    // fragment-read constants (verified layout)
    const int m    = lane & 15;
    const int l    = lane >> 4;                                // logical k-block
    const int p8   = (l ^ ((m >> 1) & 3)) * 8;                 // physical k-chunk

    f32x4 acc[8][4] = {};
    float4 qf[4], kf[4];
    float qdot = 0.f, kdot = 0.f;

    // issue global fp32 loads for tile kt_ into qf/kf (in flight across MFMA)
    #define STAGE_LOAD(kt_) do {                                                 \
        const float* aq_ = Qg + (size_t)sr * DD + (kt_) * 32 + hh * 16;          \
        const float* bk_ = Kg + (size_t)sr * DD + (kt_) * 32 + hh * 16;          \
        _Pragma("unroll")                                                        \
        for (int j_ = 0; j_ < 4; ++j_) {                                         \
            qf[j_] = ((const float4*)aq_)[j_];                                   \
            kf[j_] = ((const float4*)bk_)[j_];                                   \
        }                                                                        \
    } while (0)

    // consume qf/kf for tile kt_: logit dots (fp32), w3-scale, cvt bf16,
    // swizzled ds_write into ring slot s_ (chunks l=2hh,2hh+1 of row sr).
    #define STAGE_WRITE(kt_, s_) do {                                            \
        const int k0_ = (kt_) * 32 + hh * 16;                                    \
        unsigned qa_[8], kb_[8];                                                 \
        _Pragma("unroll")                                                        \
        for (int j_ = 0; j_ < 4; ++j_) {                                         \
            const float4 q_ = qf[j_], k_ = kf[j_];                               \
            const float a0 = w1[k0_ + 4*j_ + 0], a1 = w1[k0_ + 4*j_ + 1],        \
                        a2 = w1[k0_ + 4*j_ + 2], a3 = w1[k0_ + 4*j_ + 3];        \
            const float b0 = w2[k0_ + 4*j_ + 0], b1 = w2[k0_ + 4*j_ + 1],        \
                        b2 = w2[k0_ + 4*j_ + 2], b3 = w2[k0_ + 4*j_ + 3];        \
            const float c0 = w3[k0_ + 4*j_ + 0], c1 = w3[k0_ + 4*j_ + 1],        \
                        c2 = w3[k0_ + 4*j_ + 2], c3 = w3[k0_ + 4*j_ + 3];        \
            qdot += q_.x*a0 + q_.y*a1 + q_.z*a2 + q_.w*a3;                       \
            kdot += k_.x*b0 + k_.y*b1 + k_.z*b2 + k_.w*b3;                       \
            qa_[2*j_    ] = pack_bf16(q_.x, q_.y);                               \
            qa_[2*j_ + 1] = pack_bf16(q_.z, q_.w);                               \
            kb_[2*j_    ] = pack_bf16(k_.x * c0, k_.y * c1);                     \
            kb_[2*j_ + 1] = pack_bf16(k_.z * c2, k_.w * c3);                     \
        }                                                                        \
        const int x_ = (sr >> 1) & 3;                                            \
        unsigned short* ar_ = &As[s_][sr * 32];                                  \
        unsigned short* br_ = &Bs[s_][sr * 32];                                  \
        uint4 vq0 = {qa_[0], qa_[1], qa_[2], qa_[3]};                            \
        uint4 vq1 = {qa_[4], qa_[5], qa_[6], qa_[7]};                            \
        uint4 vk0 = {kb_[0], kb_[1], kb_[2], kb_[3]};                            \
        uint4 vk1 = {kb_[4], kb_[5], kb_[6], kb_[7]};                            \
        *(uint4*)&ar_[((2*hh    ) ^ x_) * 8] = vq0;                              \
        *(uint4*)&ar_[((2*hh + 1) ^ x_) * 8] = vq1;                              \
        *(uint4*)&br_[((2*hh    ) ^ x_) * 8] = vk0;                              \
        *(uint4*)&br_[((2*hh + 1) ^ x_) * 8] = vk1;                              \
    } while (0)

    // frag reads + lgkm drain + sched fence (rule 18) + 32 MFMA
    #define COMPUTE(s_) do {                                                     \
        const unsigned short* A_ = As[s_];                                       \
        const unsigned short* B_ = Bs[s_];                                       \
        bf16x8 av[8], bv[4];                                                     \
        _Pragma("unroll")                                                        \
        for (int tt = 0; tt < 8; ++tt)                                           \
            av[tt] = *(const bf16x8*)&A_[(wq * 128 + tt * 16 + m) * 32 + p8];    \
        _Pragma("unroll")                                                        \
        for (int tt = 0; tt < 4; ++tt)                                           \
            bv[tt] = *(const bf16x8*)&B_[(wk * 64 + tt * 16 + m) * 32 + p8];     \
        asm volatile("s_waitcnt lgkmcnt(0)" ::: "memory");                       \
        __builtin_amdgcn_sched_barrier(0);                                       \
        __builtin_amdgcn_s_setprio(1);                                           \
        _Pragma("unroll")                                                        \
        for (int at = 0; at < 8; ++at)                                           \
            _Pragma("unroll")                                                    \
            for (int bt = 0; bt < 4; ++bt)                                       \
                acc[at][bt] = __builtin_amdgcn_mfma_f32_16x16x32_bf16(           \
                    av[at], bv[bt], acc[at][bt], 0, 0, 0);                       \
        __builtin_amdgcn_s_setprio(0);                                           \
    } while (0)

    const int NT = DD / 32;   // 24 K-tiles

    // prologue: load+convert tile 0 into slot 0; tile 1's loads in flight
    STAGE_LOAD(0);
    STAGE_WRITE(0, 0);
    STAGE_LOAD(1);
    asm volatile("s_waitcnt lgkmcnt(0)" ::: "memory");
    __builtin_amdgcn_s_barrier();
    __builtin_amdgcn_sched_barrier(0);

    // steady: compute t | convert+write t+1 | issue loads t+2
    for (int t = 0; t < NT - 1; ++t) {
        COMPUTE(t & 1);
        STAGE_WRITE(t + 1, (t + 1) & 1);
        if (t + 2 < NT) STAGE_LOAD(t + 2);
        asm volatile("s_waitcnt lgkmcnt(0)" ::: "memory");
        __builtin_amdgcn_s_barrier();
        __builtin_amdgcn_sched_barrier(0);
    }
    COMPUTE((NT - 1) & 1);

    #undef STAGE_LOAD
    #undef STAGE_WRITE
    #undef COMPUTE

    // block-local logit reduction: ql[r] = partial(r,h=0) + partial(r,h=1)
    redq[tid] = qdot;
    redk[tid] = kdot;
    __syncthreads();
    if (tid < 256) {
        qls[tid] = redq[tid] + redq[tid + 256];
        kls[tid] = redk[tid] + redk[tid + 256];
    }
    __syncthreads();

    // epilogue: C/D layout col = lane&15, row = (lane>>4)*4 + reg  [m89/m91]
    const int qrow0 = qt * 256 + wq * 128;
    const int kcol0 = kt * 256 + wk * 64;
    float* outp = out + ((size_t)b * LL + qrow0) * LL + kcol0;
    const int col = lane & 15, r4 = (lane >> 4) * 4;

    #pragma unroll
    for (int at = 0; at < 8; ++at) {
        #pragma unroll
        for (int bt = 0; bt < 4; ++bt) {
            const float klv = kls[wk * 64 + bt * 16 + col];
            #pragma unroll
            for (int r = 0; r < 4; ++r) {
                const int row = at * 16 + r4 + r;
                outp[(size_t)row * LL + bt * 16 + col] =
                    acc[at][bt][r] + qls[wq * 128 + row] + klv;
            }
        }
    }
}

extern "C" void kernel_launch(void* const* d_in, const int* in_sizes, int n_in,
                              void* d_out, int out_size, void* d_ws, size_t ws_size,
                              hipStream_t stream) {
    const float* Q  = (const float*)d_in[0];
    const float* K  = (const float*)d_in[1];
    const float* w1 = (const float*)d_in[2];
    const float* w2 = (const float*)d_in[3];
    const float* w3 = (const float*)d_in[4];
    float* out = (float*)d_out;

    (void)d_ws; (void)ws_size;  // fused kernel needs no workspace

    trilinear_fused<<<512, 512, 0, stream>>>(Q, K, w1, w2, w3, out);
}